// Round 11
// baseline (748.042 us; speedup 1.0000x reference)
//
#include <hip/hip_runtime.h>
#include <math.h>

// Problem constants
#define KCODES 1024
#define DDIM   64

// Output layout (floats), concatenated in reference return order:
// z_q_out [16,64,64,64], idx_out [16,64,64], emb_new [64,1024],
// emb_ema_new [64,1024], counts_ema_new [1024]
constexpr size_t O_ZQ  = 0;
constexpr size_t O_IDX = 4194304;
constexpr size_t O_EMB = O_IDX + 65536;   // 4259840
constexpr size_t O_EMA = O_EMB + 65536;   // 4325376
constexpr size_t O_CEN = O_EMA + 65536;   // 4390912

// Workspace layout (float offsets)
constexpr size_t W_UPD   = 0;              // [K][D] segment-sum accumulator
constexpr size_t W_CNT   = 65536;          // [K] histogram
constexpr size_t W_ENORM = W_CNT + 1024;   // [K] ||e_k||^2
constexpr size_t W_EMBT  = W_ENORM + 1024; // [K][D] transposed codebook

// ---------------------------------------------------------------------------
// K1: LDS-tiled transpose emb[D][K] -> embT[K][D], eNorm, zero W_UPD/W_CNT.
// 16 blocks; block g handles codes k0 = g*64 .. k0+63.  (verbatim from R7)
__global__ __launch_bounds__(256) void vq_prep(const float* __restrict__ emb,
                                               float* __restrict__ ws) {
  __shared__ float t_lds[64 * 65];          // [d][k] padded (+1)
  const int tid = threadIdx.x;
  const int g   = blockIdx.x;
  const int k0  = g * 64;

  #pragma unroll
  for (int it = 0; it < 16; ++it) {
    const int idx = tid + it * 256;         // 0..4095
    const int d   = idx >> 6;
    const int kq  = idx & 63;
    t_lds[d * 65 + kq] = emb[d * KCODES + k0 + kq];
  }
  __syncthreads();

  #pragma unroll
  for (int it = 0; it < 16; ++it) {
    const int idx = tid + it * 256;
    const int k   = idx >> 6;
    const int d   = idx & 63;
    ws[W_EMBT + (size_t)(k0 + k) * 64 + d] = t_lds[d * 65 + k];
  }

  if (tid < 64) {
    const int k = tid;
    float s = 0.f;
    #pragma unroll
    for (int d = 0; d < DDIM; ++d) {
      const float v = t_lds[d * 65 + k];
      s = fmaf(v, v, s);
    }
    ws[W_ENORM + k0 + k] = s;
  }

  float4* u4 = (float4*)(ws + W_UPD);
  #pragma unroll
  for (int j = 0; j < 4; ++j) u4[g * 1024 + tid + j * 256] = float4{0.f, 0.f, 0.f, 0.f};
  if (tid < 64) ws[W_CNT + k0 + tid] = 0.f;
}

// ---------------------------------------------------------------------------
// K2: tiled distance GEMM + argmin + fused epilogue.
// 1024 blocks x 256 threads; block = 64 rows x full K.
// Thread map: rowgrp = tid>>5 (8 grps x 8 rows), colgrp = tid&31; per-thread
// 8 rows x 16 codes: code = c0 + colgrp*4 + q*128 + j over 512-code chunks
// (2 chunks x 4 d-phases = 8 stage-barriers, half of R7's 16).
// Per dp: 6 ds_read_b128 per 128 FMAs -> LDS demand 147K cyc/CU vs 131K VALU.
// LDS: z 64x68 = 17.4 KB + e 16x512 = 32 KB + bidx -> ~50 KB -> 3 blocks/CU;
// registers ~164 total (R10 evidence) fit 3 waves/EU -> launch_bounds(256,3).
#define ZP 68
__global__ __launch_bounds__(256, 3) void vq_main(
    const float* __restrict__ z_e,
    const float* __restrict__ emb,    // native [D][K]
    const float* __restrict__ embT,   // ws + W_EMBT  [K][D] (epilogue A)
    const float* __restrict__ eN,     // ws + W_ENORM [K]
    float* __restrict__ upd,          // ws + W_UPD   [K][D]
    float* __restrict__ cnt,          // ws + W_CNT   [K]
    float* __restrict__ out) {
  __shared__ float z_lds[DDIM * ZP];  // [d][row] padded (stride 68)
  __shared__ float e_lds[16 * 512];   // [dp][code]  32 KB
  __shared__ int   bidx[64];

  const int tid    = threadIdx.x;
  const int bid    = blockIdx.x;
  const int wv     = tid >> 6;
  const int lane   = tid & 63;
  const int colgrp = tid & 31;        // 0..31 (lane bits 0..4)
  const int rowgrp = tid >> 5;        // 0..7
  const int r0     = rowgrp * 8;
  const int c0t    = colgrp * 4;

  const int n0  = bid * 64;           // block's first row id
  const int b   = n0 >> 12;
  const int hw0 = n0 & 4095;          // multiple of 64
  const size_t zbase = (size_t)b * 262144 + (size_t)hw0;

  const float4* __restrict__ eg = (const float4*)emb;

  // ---- stage z tile [64][64] (coalesced 256B segments per instr) ----
  {
    const float4* z4 = (const float4*)(z_e + zbase);   // + d*1024 (float4)
    #pragma unroll
    for (int it = 0; it < 4; ++it) {
      const int f  = tid + it * 256;   // 0..1023
      const int d  = f >> 4;           // 0..63
      const int r4 = f & 15;           // float4 within row
      const float4 v = z4[(size_t)d * 1024 + r4];
      *(float4*)(z_lds + d * ZP + r4 * 4) = v;
    }
  }

  float minval[8];
  int   minidx[8];
  #pragma unroll
  for (int i = 0; i < 8; ++i) { minval[i] = INFINITY; minidx[i] = 0; }

  #pragma unroll 1
  for (int chunk = 0; chunk < 2; ++chunk) {
    const int c0 = chunk * 512;

    float acc[8][16];
    #pragma unroll
    for (int i = 0; i < 8; ++i)
      #pragma unroll
      for (int j = 0; j < 16; ++j) acc[i][j] = 0.f;

    #pragma unroll 1
    for (int pp = 0; pp < 4; ++pp) {
      const int dstart = pp * 16;
      __syncthreads();   // previous phase's e_lds readers done
      // ---- stage e tile [16][512] <- emb[dstart+dp][c0..c0+511] ----
      {
        #pragma unroll
        for (int it = 0; it < 8; ++it) {
          const int f  = tid + it * 256;   // 0..2047
          const int dp = f >> 7;           // 0..15
          const int c4 = f & 127;          // float4 within 512-code row
          const float4 v = eg[(size_t)(dstart + dp) * 256 + (c0 >> 2) + c4];
          *(float4*)(e_lds + dp * 512 + c4 * 4) = v;
        }
      }
      __syncthreads();

      #pragma unroll 4
      for (int dp = 0; dp < 16; ++dp) {
        const int d = dstart + dp;
        float zf[8], ef[16];
        const float4 za = *(const float4*)(z_lds + d * ZP + r0);
        const float4 zb = *(const float4*)(z_lds + d * ZP + r0 + 4);
        zf[0]=za.x; zf[1]=za.y; zf[2]=za.z; zf[3]=za.w;
        zf[4]=zb.x; zf[5]=zb.y; zf[6]=zb.z; zf[7]=zb.w;
        #pragma unroll
        for (int q = 0; q < 4; ++q) {
          const float4 ev = *(const float4*)(e_lds + dp * 512 + c0t + q * 128);
          ef[4*q+0]=ev.x; ef[4*q+1]=ev.y; ef[4*q+2]=ev.z; ef[4*q+3]=ev.w;
        }
        #pragma unroll
        for (int i = 0; i < 8; ++i)
          #pragma unroll
          for (int j = 0; j < 16; ++j)
            acc[i][j] = fmaf(zf[i], ef[j], acc[i][j]);
      }
    }

    // ---- fold chunk into running argmin (index-ascending order) ----
    float en[16];
    #pragma unroll
    for (int q = 0; q < 4; ++q) {
      const float4 v = *(const float4*)(eN + c0 + c0t + q * 128);
      en[4*q+0]=v.x; en[4*q+1]=v.y; en[4*q+2]=v.z; en[4*q+3]=v.w;
    }
    #pragma unroll
    for (int i = 0; i < 8; ++i) {
      #pragma unroll
      for (int q = 0; q < 4; ++q) {
        #pragma unroll
        for (int j = 0; j < 4; ++j) {
          const int jj = q * 4 + j;
          const float val = fmaf(-2.f, acc[i][jj], en[jj]);  // ||e||^2 - 2 z.e
          if (val < minval[i]) {
            minval[i] = val;
            minidx[i] = c0 + c0t + q * 128 + j;
          }
        }
      }
    }
  }

  // ---- cross-colgrp argmin: butterfly over lane bits 0..4 ----
  #pragma unroll
  for (int i = 0; i < 8; ++i) {
    float v = minval[i];
    int  ix = minidx[i];
    #pragma unroll
    for (int m = 1; m < 32; m <<= 1) {
      const float v2 = __shfl_xor(v, m, 64);
      const int   i2 = __shfl_xor(ix, m, 64);
      if (v2 < v || (v2 == v && i2 < ix)) { v = v2; ix = i2; }
    }
    minidx[i] = ix;   // lanes within each 32-half agree
  }

  if (colgrp == 0) {  // 2 lanes per wave, 8 writers total, 8 rows each
    #pragma unroll
    for (int i = 0; i < 8; ++i) {
      const int row = r0 + i;
      const int bi  = minidx[i];
      bidx[row] = bi;
      out[O_IDX + n0 + row] = (float)bi;
      atomicAdd(cnt + bi, 1.0f);
    }
  }
  __syncthreads();

  // ---- epilogue A: z_q = z + (e - z); coalesced stores over rows ----
  {
    const int row  = tid & 63;
    const int dgrp = tid >> 6;          // 4 groups x 16 d
    const int code = bidx[row];
    const float4* er4 = (const float4*)(embT + (size_t)code * 64);
    #pragma unroll
    for (int q = 0; q < 4; ++q) {
      const float4 e4 = er4[dgrp * 4 + q];
      const float ev[4] = {e4.x, e4.y, e4.z, e4.w};
      #pragma unroll
      for (int x = 0; x < 4; ++x) {
        const int d = dgrp * 16 + q * 4 + x;
        const float zv = z_lds[d * ZP + row];
        out[O_ZQ + zbase + (size_t)d * 4096 + row] = zv + (ev[x] - zv);
      }
    }
  }

  // ---- epilogue B: segment-sum; one coalesced atomic instruction per row ----
  {
    #pragma unroll 4
    for (int rr = 0; rr < 16; ++rr) {
      const int row  = wv * 16 + rr;
      const int code = bidx[row];
      atomicAdd(upd + (size_t)code * 64 + lane, z_lds[lane * ZP + row]);
    }
  }
}

// ---------------------------------------------------------------------------
// K3: EMA updates + normalization. Each block redundantly reduces n.
__global__ __launch_bounds__(256) void vq_final(const float* __restrict__ emb_ema,
                                                const float* __restrict__ counts_ema,
                                                const float* __restrict__ ws,
                                                float* __restrict__ out) {
  __shared__ float red[256];
  const int tid = threadIdx.x;
  const float* cnt = ws + W_CNT;

  float psum = 0.f;
  for (int t = tid; t < KCODES; t += 256) {
    const float ce  = counts_ema[t];
    const float cen = ce + 0.01f * (cnt[t] - ce);
    psum += cen;
    if (blockIdx.x == 0) out[O_CEN + t] = cen;
  }
  red[tid] = psum;
  __syncthreads();
  #pragma unroll
  for (int s = 128; s > 0; s >>= 1) {
    if (tid < s) red[tid] += red[tid + s];
    __syncthreads();
  }
  const float nsum = red[0];

  const int i = blockIdx.x * 256 + tid;   // 0..65535 over [D][K]
  const int d = i >> 10;
  const int k = i & 1023;

  const float ce  = counts_ema[k];
  const float cen = ce + 0.01f * (cnt[k] - ce);
  const float norm = (cen + 1e-5f) / (nsum + (float)KCODES * 1e-5f) * nsum;

  const float ema     = emb_ema[i];
  const float ema_new = ema + 0.01f * (ws[W_UPD + (size_t)k * 64 + d] - ema);
  out[O_EMA + i] = ema_new;
  out[O_EMB + i] = ema_new / norm;
}

// ---------------------------------------------------------------------------
extern "C" void kernel_launch(void* const* d_in, const int* in_sizes, int n_in,
                              void* d_out, int out_size, void* d_ws, size_t ws_size,
                              hipStream_t stream) {
  const float* z_e        = (const float*)d_in[0];
  const float* emb        = (const float*)d_in[1];
  const float* emb_ema    = (const float*)d_in[2];
  const float* counts_ema = (const float*)d_in[3];
  float* out = (float*)d_out;
  float* ws  = (float*)d_ws;

  vq_prep<<<16, 256, 0, stream>>>(emb, ws);
  vq_main<<<1024, 256, 0, stream>>>(z_e, emb, ws + W_EMBT, ws + W_ENORM,
                                    ws + W_UPD, ws + W_CNT, out);
  vq_final<<<256, 256, 0, stream>>>(emb_ema, counts_ema, ws, out);
}

// Round 12
// 207.713 us; speedup vs baseline: 3.6013x; 3.6013x over previous
//
#include <hip/hip_runtime.h>
#include <math.h>

// Problem constants
#define KCODES 1024
#define DDIM   64

typedef __bf16 bf16x8 __attribute__((ext_vector_type(8)));
typedef float  f32x4  __attribute__((ext_vector_type(4)));

// Output layout (floats), concatenated in reference return order:
// z_q_out [16,64,64,64], idx_out [16,64,64], emb_new [64,1024],
// emb_ema_new [64,1024], counts_ema_new [1024]
constexpr size_t O_ZQ  = 0;
constexpr size_t O_IDX = 4194304;
constexpr size_t O_EMB = O_IDX + 65536;   // 4259840
constexpr size_t O_EMA = O_EMB + 65536;   // 4325376
constexpr size_t O_CEN = O_EMA + 65536;   // 4390912

// Workspace layout (float offsets). e-splits are bf16 [K][64] arrays.
constexpr size_t W_UPD   = 0;              // [K][D] segment-sum accumulator
constexpr size_t W_CNT   = 65536;          // [K] histogram
constexpr size_t W_ENORM = W_CNT + 1024;   // [K] ||e_k||^2 fp32
constexpr size_t W_EHI   = W_ENORM + 1024; // [K][64] bf16 (32768 floats)
constexpr size_t W_EMID  = W_EHI  + 32768;
constexpr size_t W_ELO   = W_EMID + 32768; // end: 165888 floats (~663 KB)

// ---------------------------------------------------------------------------
// K1: transpose-stage emb, compute eNorm + 3-way bf16 splits, zero accums.
// 16 blocks; block g handles codes k0 = g*64 .. k0+63.
__global__ __launch_bounds__(256) void vq_prep(const float* __restrict__ emb,
                                               float* __restrict__ ws) {
  __shared__ float t_lds[64 * 65];          // [d][k] padded (+1)
  const int tid = threadIdx.x;
  const int g   = blockIdx.x;
  const int k0  = g * 64;

  #pragma unroll
  for (int it = 0; it < 16; ++it) {
    const int idx = tid + it * 256;         // 0..4095
    const int d   = idx >> 6;
    const int kq  = idx & 63;
    t_lds[d * 65 + kq] = emb[d * KCODES + k0 + kq];
  }
  __syncthreads();

  // bf16 splits: e = hi + mid + lo (each RTNE), stored [code][d]
  __bf16* ehi = (__bf16*)(ws + W_EHI);
  __bf16* emi = (__bf16*)(ws + W_EMID);
  __bf16* elo = (__bf16*)(ws + W_ELO);
  #pragma unroll
  for (int it = 0; it < 16; ++it) {
    const int idx = tid + it * 256;
    const int k   = idx >> 6;
    const int d   = idx & 63;
    const float v = t_lds[d * 65 + k];
    const __bf16 h = (__bf16)v;
    const float r1 = v - (float)h;
    const __bf16 m = (__bf16)r1;
    const __bf16 l = (__bf16)(r1 - (float)m);
    const size_t o = (size_t)(k0 + k) * 64 + d;
    ehi[o] = h; emi[o] = m; elo[o] = l;
  }

  if (tid < 64) {
    const int k = tid;
    float s = 0.f;
    #pragma unroll
    for (int d = 0; d < DDIM; ++d) {
      const float v = t_lds[d * 65 + k];
      s = fmaf(v, v, s);
    }
    ws[W_ENORM + k0 + k] = s;
  }

  float4* u4 = (float4*)(ws + W_UPD);
  #pragma unroll
  for (int j = 0; j < 4; ++j) u4[g * 1024 + tid + j * 256] = float4{0.f, 0.f, 0.f, 0.f};
  if (tid < 64) ws[W_CNT + k0 + tid] = 0.f;
}

// ---------------------------------------------------------------------------
// K2: MFMA distance GEMM + argmin + fused epilogue.
// 512 blocks x 256 threads (4 waves); block = 128 rows; wave = 32 rows
// (2 M-tiles of 16x16x32 bf16) x all 1024 codes (64 N-tiles).
// z 3-split fragments live in VGPRs (extracted once from z_lds);
// e-split fragments stream from L2 (bf16 [code][d] arrays) with depth-1
// register ping-pong prefetch. NO barriers in the hot loop.
// Fold: C layout col=lane&15 (code), row=(lane>>4)*4+reg [m89-verified].
#define ZP2 132
__global__ __launch_bounds__(256, 2) void vq_main(
    const float* __restrict__ z_e,
    const float* __restrict__ ws_ro,  // read-only alias of ws
    float* __restrict__ upd,          // ws + W_UPD   [K][D]
    float* __restrict__ cnt,          // ws + W_CNT   [K]
    float* __restrict__ out) {
  __shared__ float z_lds[DDIM * ZP2]; // [d][row] padded (stride 132)
  __shared__ int   bidx[128];

  const int tid  = threadIdx.x;
  const int bid  = blockIdx.x;
  const int wv   = tid >> 6;
  const int lane = tid & 63;
  const int col  = lane & 15;         // MFMA col (code within tile)
  const int kb   = lane >> 4;         // k-block (0..3)

  const int n0  = bid * 128;          // block's first row id
  const int b   = n0 >> 12;
  const int hw0 = n0 & 4095;          // multiple of 128
  const size_t zbase = (size_t)b * 262144 + (size_t)hw0;

  const float*  __restrict__ eN  = ws_ro + W_ENORM;
  const __bf16* __restrict__ ehi = (const __bf16*)(ws_ro + W_EHI);
  const __bf16* __restrict__ emi = (const __bf16*)(ws_ro + W_EMID);
  const __bf16* __restrict__ elo = (const __bf16*)(ws_ro + W_ELO);

  // ---- stage z tile [64][128] (coalesced 512B segments per instr) ----
  {
    const float4* z4 = (const float4*)(z_e + zbase);   // + d*1024 (float4)
    #pragma unroll
    for (int it = 0; it < 8; ++it) {
      const int f  = tid + it * 256;   // 0..2047
      const int d  = f >> 5;           // 0..63
      const int r4 = f & 31;           // float4 within row
      const float4 v = z4[(size_t)d * 1024 + r4];
      *(float4*)(z_lds + d * ZP2 + r4 * 4) = v;
    }
  }
  __syncthreads();

  // ---- extract z fragments (A-operand) + 3-way split, once ----
  // A[m][k]: lane holds m=col (row), k = kb*8+j ; d = ks*32 + kb*8 + j
  bf16x8 zh[2][2], zm[2][2], zl[2][2];   // [Mtile][ks]
  #pragma unroll
  for (int t = 0; t < 2; ++t) {
    const int row = wv * 32 + t * 16 + col;
    #pragma unroll
    for (int ks = 0; ks < 2; ++ks) {
      #pragma unroll
      for (int j = 0; j < 8; ++j) {
        const int d = ks * 32 + kb * 8 + j;
        const float v = z_lds[d * ZP2 + row];
        const __bf16 h = (__bf16)v;
        const float r1 = v - (float)h;
        const __bf16 m = (__bf16)r1;
        zh[t][ks][j] = h;
        zm[t][ks][j] = m;
        zl[t][ks][j] = (__bf16)(r1 - (float)m);
      }
    }
  }

  // per-lane e-frag base: code = n0c + col, d-offset kb*8 (+ks*32)
  const size_t ebase = (size_t)col * 64 + (size_t)kb * 8;

  float minval[2][4];
  int   minidx[2][4];
  #pragma unroll
  for (int t = 0; t < 2; ++t)
    #pragma unroll
    for (int i = 0; i < 4; ++i) { minval[t][i] = INFINITY; minidx[t][i] = 0; }

  bf16x8 Ah[2], Am[2], Al[2]; float Aen;
  bf16x8 Bh[2], Bm[2], Bl[2]; float Ben;

  // load fragment set for tile n
  auto loadF = [&](int n, bf16x8 (&fh)[2], bf16x8 (&fm)[2], bf16x8 (&fl)[2],
                   float& fen) {
    const size_t o = ebase + (size_t)n * 1024;   // n*16 codes * 64 d
    fh[0] = *(const bf16x8*)(ehi + o);
    fh[1] = *(const bf16x8*)(ehi + o + 32);
    fm[0] = *(const bf16x8*)(emi + o);
    fm[1] = *(const bf16x8*)(emi + o + 32);
    fl[0] = *(const bf16x8*)(elo + o);
    fl[1] = *(const bf16x8*)(elo + o + 32);
    fen = eN[n * 16 + col];
  };

  // compute tile n with fragment set (12 MFMA per M-tile, smallest-first)
  auto compF = [&](int n, bf16x8 (&fh)[2], bf16x8 (&fm)[2], bf16x8 (&fl)[2],
                   float fen) {
    const int code = n * 16 + col;
    #pragma unroll
    for (int t = 0; t < 2; ++t) {
      f32x4 acc = {0.f, 0.f, 0.f, 0.f};
      #pragma unroll
      for (int ks = 0; ks < 2; ++ks)
        acc = __builtin_amdgcn_mfma_f32_16x16x32_bf16(zl[t][ks], fh[ks], acc, 0, 0, 0);
      #pragma unroll
      for (int ks = 0; ks < 2; ++ks)
        acc = __builtin_amdgcn_mfma_f32_16x16x32_bf16(zh[t][ks], fl[ks], acc, 0, 0, 0);
      #pragma unroll
      for (int ks = 0; ks < 2; ++ks)
        acc = __builtin_amdgcn_mfma_f32_16x16x32_bf16(zm[t][ks], fm[ks], acc, 0, 0, 0);
      #pragma unroll
      for (int ks = 0; ks < 2; ++ks)
        acc = __builtin_amdgcn_mfma_f32_16x16x32_bf16(zm[t][ks], fh[ks], acc, 0, 0, 0);
      #pragma unroll
      for (int ks = 0; ks < 2; ++ks)
        acc = __builtin_amdgcn_mfma_f32_16x16x32_bf16(zh[t][ks], fm[ks], acc, 0, 0, 0);
      #pragma unroll
      for (int ks = 0; ks < 2; ++ks)
        acc = __builtin_amdgcn_mfma_f32_16x16x32_bf16(zh[t][ks], fh[ks], acc, 0, 0, 0);
      #pragma unroll
      for (int i = 0; i < 4; ++i) {
        const float val = fmaf(-2.f, acc[i], fen);   // ||e||^2 - 2 z.e
        if (val < minval[t][i]) { minval[t][i] = val; minidx[t][i] = code; }
      }
    }
  };

  // ---- barrier-free hot loop with depth-1 ping-pong prefetch ----
  loadF(0, Ah, Am, Al, Aen);
  #pragma unroll 1
  for (int n = 0; n < 64; n += 2) {
    loadF(n + 1, Bh, Bm, Bl, Ben);
    compF(n, Ah, Am, Al, Aen);
    if (n < 62) loadF(n + 2, Ah, Am, Al, Aen);
    compF(n + 1, Bh, Bm, Bl, Ben);
  }

  // ---- cross-lane argmin: butterfly over lane bits 0..3 (col bits) ----
  #pragma unroll
  for (int t = 0; t < 2; ++t) {
    #pragma unroll
    for (int i = 0; i < 4; ++i) {
      float v = minval[t][i];
      int  ix = minidx[t][i];
      #pragma unroll
      for (int m = 1; m < 16; m <<= 1) {
        const float v2 = __shfl_xor(v, m, 64);
        const int   i2 = __shfl_xor(ix, m, 64);
        if (v2 < v || (v2 == v && i2 < ix)) { v = v2; ix = i2; }
      }
      minidx[t][i] = ix;   // all 16 lanes of the quarter agree
    }
  }

  if (col == 0) {   // 4 writer lanes per wave (one per quarter), 8 rows each
    #pragma unroll
    for (int t = 0; t < 2; ++t) {
      #pragma unroll
      for (int i = 0; i < 4; ++i) {
        const int row = wv * 32 + t * 16 + kb * 4 + i;
        const int bi  = minidx[t][i];
        bidx[row] = bi;
        out[O_IDX + n0 + row] = (float)bi;
        atomicAdd(cnt + bi, 1.0f);
      }
    }
  }
  __syncthreads();

  // ---- epilogue A: z_q = z + (e' - z), e' = hi+mid+lo (err ~2^-27) ----
  {
    const int row   = tid & 127;
    const int dhalf = tid >> 7;         // 2 groups x 32 d
    const int code  = bidx[row];
    const size_t eo = (size_t)code * 64 + dhalf * 32;
    const bf16x8* ph = (const bf16x8*)(ehi + eo);
    const bf16x8* pm = (const bf16x8*)(emi + eo);
    const bf16x8* pl = (const bf16x8*)(elo + eo);
    #pragma unroll
    for (int q = 0; q < 4; ++q) {
      const bf16x8 vh = ph[q], vm = pm[q], vl = pl[q];
      #pragma unroll
      for (int x = 0; x < 8; ++x) {
        const int d = dhalf * 32 + q * 8 + x;
        const float e  = (float)vh[x] + (float)vm[x] + (float)vl[x];
        const float zv = z_lds[d * ZP2 + row];
        out[O_ZQ + zbase + (size_t)d * 4096 + row] = zv + (e - zv);
      }
    }
  }

  // ---- epilogue B: segment-sum; one coalesced atomic instruction per row ----
  {
    #pragma unroll 4
    for (int rr = 0; rr < 32; ++rr) {
      const int row  = wv * 32 + rr;
      const int code = bidx[row];
      atomicAdd(upd + (size_t)code * 64 + lane, z_lds[lane * ZP2 + row]);
    }
  }
}

// ---------------------------------------------------------------------------
// K3: EMA updates + normalization. Each block redundantly reduces n.
__global__ __launch_bounds__(256) void vq_final(const float* __restrict__ emb_ema,
                                                const float* __restrict__ counts_ema,
                                                const float* __restrict__ ws,
                                                float* __restrict__ out) {
  __shared__ float red[256];
  const int tid = threadIdx.x;
  const float* cnt = ws + W_CNT;

  float psum = 0.f;
  for (int t = tid; t < KCODES; t += 256) {
    const float ce  = counts_ema[t];
    const float cen = ce + 0.01f * (cnt[t] - ce);
    psum += cen;
    if (blockIdx.x == 0) out[O_CEN + t] = cen;
  }
  red[tid] = psum;
  __syncthreads();
  #pragma unroll
  for (int s = 128; s > 0; s >>= 1) {
    if (tid < s) red[tid] += red[tid + s];
    __syncthreads();
  }
  const float nsum = red[0];

  const int i = blockIdx.x * 256 + tid;   // 0..65535 over [D][K]
  const int d = i >> 10;
  const int k = i & 1023;

  const float ce  = counts_ema[k];
  const float cen = ce + 0.01f * (cnt[k] - ce);
  const float norm = (cen + 1e-5f) / (nsum + (float)KCODES * 1e-5f) * nsum;

  const float ema     = emb_ema[i];
  const float ema_new = ema + 0.01f * (ws[W_UPD + (size_t)k * 64 + d] - ema);
  out[O_EMA + i] = ema_new;
  out[O_EMB + i] = ema_new / norm;
}

// ---------------------------------------------------------------------------
extern "C" void kernel_launch(void* const* d_in, const int* in_sizes, int n_in,
                              void* d_out, int out_size, void* d_ws, size_t ws_size,
                              hipStream_t stream) {
  const float* z_e        = (const float*)d_in[0];
  const float* emb        = (const float*)d_in[1];
  const float* emb_ema    = (const float*)d_in[2];
  const float* counts_ema = (const float*)d_in[3];
  float* out = (float*)d_out;
  float* ws  = (float*)d_ws;

  vq_prep<<<16, 256, 0, stream>>>(emb, ws);
  vq_main<<<512, 256, 0, stream>>>(z_e, ws, ws + W_UPD, ws + W_CNT, out);
  vq_final<<<256, 256, 0, stream>>>(emb_ema, counts_ema, ws, out);
}